// Round 4
// baseline (545.285 us; speedup 1.0000x reference)
//
#include <hip/hip_runtime.h>
#include <hip/hip_bf16.h>

// Problem constants
#define NN 8192   // nodes
#define KD 256    // feature size (GEMM K)

typedef __bf16 bf16x8 __attribute__((ext_vector_type(8)));
typedef float  f32x4  __attribute__((ext_vector_type(4)));
typedef int    i32x4  __attribute__((ext_vector_type(4)));
typedef unsigned short u16x8 __attribute__((ext_vector_type(8)));

union frag_u { i32x4 i; bf16x8 b; };

// ---------------------------------------------------------------------------
// Workspace layout (ws_size >= 1 GiB per round-3 profile: fill WRITE_SIZE=1GiB)
//   G      bf16[NN][KD]  at 0      (4 MB)    G[i][s] = sqrt(|wq_s wk_s|) f_si
//   summed f32[NN]       at 4MB    (32 KB)
//   inv    f32[NN]       at 4MB+32K(32 KB)
//   smask  u32[KD/2]     at 4MB+64K(512 B)   bf16-pair sign masks of w_s
//   E      bf16[NN][NN]  at 8MB    (128 MB)  E[i][j] = exp(C[i][j])
// ---------------------------------------------------------------------------
#define G_OFF      0
#define SUM_OFF    (4u * 1024 * 1024)
#define INV_OFF    (SUM_OFF + 32u * 1024)
#define SMASK_OFF  (INV_OFF + 32u * 1024)
#define E_OFF      (8u * 1024 * 1024)

// ---------------------------------------------------------------------------
// Stage a 128-row x 64-col bf16 tile (16 KB) from row-major [*, 256] source
// into LDS via global_load_lds width=16. T2 XOR swizzle applied on the global
// source side (m173 pattern); swizzle is 16B-granular so lane segments stay
// contiguous. (verified correct: round-3 absmax 1.9e-6)
// ---------------------------------------------------------------------------
__device__ __forceinline__ void stage_tile(const char* src00, char* lds,
                                           int wave, int lane) {
#pragma unroll
  for (int c = 0; c < 4; ++c) {
    const int chunk = ((wave << 2) + c) << 10;       // 1 KB per wave-call
    const int o     = chunk + (lane << 4);
    const int row   = o >> 7;
    const int swb   = o & 127;
    const int colb  = swb ^ ((row & 7) << 4);        // inverse swizzle on source
    __builtin_amdgcn_global_load_lds(
        (const __attribute__((address_space(1))) void*)(src00 + (size_t)row * (KD * 2) + colb),
        (__attribute__((address_space(3))) void*)(lds + chunk),  // wave-uniform base
        16, 0, 0);
  }
}

__device__ __forceinline__ bf16x8 read_frag(const char* lds, int row, int colb) {
  const int addr = (row << 7) + (colb ^ ((row & 7) << 4));
  return *(const bf16x8*)(lds + addr);   // ds_read_b128
}

// B-side fragment with sign(w_s) applied via bf16 sign-bit XOR.
__device__ __forceinline__ bf16x8 read_frag_sgn(const char* lds, int row, int colb,
                                                i32x4 msk) {
  const int addr = (row << 7) + (colb ^ ((row & 7) << 4));
  frag_u u;
  u.i = *(const i32x4*)(lds + addr) ^ msk;
  return u.b;
}

// ---------------------------------------------------------------------------
// prep: G[i][s] = bf16( sqrt(|wq_s*wk_s|) * f[s][i] )   (transposed)
// ---------------------------------------------------------------------------
__global__ void prep_kernel(const float* __restrict__ f,
                            const float* __restrict__ wq,
                            const float* __restrict__ wk,
                            __hip_bfloat16* __restrict__ G) {
  __shared__ float tile[32][33];
  const int i0 = blockIdx.x * 32;
  const int s0 = blockIdx.y * 32;
  const int tx = threadIdx.x, ty = threadIdx.y;   // block (32, 8)
#pragma unroll
  for (int k = 0; k < 4; ++k) {
    const int s = s0 + ty + k * 8;
    tile[ty + k * 8][tx] = f[(size_t)s * NN + i0 + tx];
  }
  __syncthreads();
  const float w  = wq[s0 + tx] * wk[s0 + tx];
  const float sq = sqrtf(fabsf(w));
#pragma unroll
  for (int k = 0; k < 4; ++k) {
    const int ii = ty + k * 8;
    G[(size_t)(i0 + ii) * KD + s0 + tx] = __float2bfloat16(sq * tile[tx][ii]);
  }
}

// ---------------------------------------------------------------------------
// init: zero summed; block 0 also builds the bf16-pair sign masks of w.
// ---------------------------------------------------------------------------
__global__ void init_kernel(const float* __restrict__ wq,
                            const float* __restrict__ wk,
                            float* __restrict__ summed,
                            unsigned* __restrict__ smask) {
  const int j = blockIdx.x * 256 + threadIdx.x;
  summed[j] = 0.0f;
  if (blockIdx.x == 0 && threadIdx.x < KD / 2) {
    const int t = threadIdx.x;
    const float w0 = wq[2 * t] * wk[2 * t];
    const float w1 = wq[2 * t + 1] * wk[2 * t + 1];
    unsigned m = 0;
    if (w0 < 0.0f) m |= 0x00008000u;
    if (w1 < 0.0f) m |= 0x80000000u;
    smask[t] = m;
  }
}

// ---------------------------------------------------------------------------
// pass1: one 128x128 tile per block. GEMM -> e=exp(C) -> store E (bf16)
//        -> masked row-sum via nbr -> one atomic per row per block.
// grid: 64 x 64 = 4096 blocks, 4 waves each.
// ---------------------------------------------------------------------------
__global__ __launch_bounds__(256, 2)
void pass1_kernel(const __hip_bfloat16* __restrict__ G,
                  const unsigned* __restrict__ smask,
                  const int* __restrict__ nbr,
                  __hip_bfloat16* __restrict__ E,
                  float* __restrict__ summed) {
  __shared__ __attribute__((aligned(128))) char lA[16384];
  __shared__ __attribute__((aligned(128))) char lB[16384];
  __shared__ __attribute__((aligned(16))) unsigned smem_mask[KD / 2];
  const int lane = threadIdx.x & 63;
  const int wave = threadIdx.x >> 6;
  const int wr = wave >> 1, wc = wave & 1;
  const int bm = blockIdx.x >> 6;
  const int bn = blockIdx.x & 63;
  const int row0 = bm * 128;
  const int col0 = bn * 128;

  if (threadIdx.x < KD / 2) smem_mask[threadIdx.x] = smask[threadIdx.x];

  f32x4 acc[4][4] = {{}};
#pragma unroll
  for (int kk = 0; kk < KD; kk += 64) {
    stage_tile((const char*)G + (size_t)row0 * (KD * 2) + kk * 2, lA, wave, lane);
    stage_tile((const char*)G + (size_t)col0 * (KD * 2) + kk * 2, lB, wave, lane);
    asm volatile("s_waitcnt vmcnt(0)" ::: "memory");
    __syncthreads();
#pragma unroll
    for (int kh = 0; kh < 2; ++kh) {
      const int colb = kh * 64 + ((lane >> 4) << 4);
      const i32x4 msk = *(const i32x4*)&smem_mask[(kk >> 1) + kh * 16 + ((lane >> 4) << 2)];
      bf16x8 a[4], b[4];
#pragma unroll
      for (int m = 0; m < 4; ++m) a[m] = read_frag(lA, wr * 64 + m * 16 + (lane & 15), colb);
#pragma unroll
      for (int n = 0; n < 4; ++n) b[n] = read_frag_sgn(lB, wc * 64 + n * 16 + (lane & 15), colb, msk);
#pragma unroll
      for (int m = 0; m < 4; ++m)
#pragma unroll
        for (int n = 0; n < 4; ++n)
          acc[m][n] = __builtin_amdgcn_mfma_f32_16x16x32_bf16(a[m], b[n], acc[m][n], 0, 0, 0);
    }
    __syncthreads();
  }

  // epilogue: exp, E-store, masked accumulate.
  // C/D layout: col = lane&15, row = (lane>>4)*4 + r  (verified round 3)
  float rsum[4][4] = {};
  const int roww = row0 + wr * 64;
  const int colw = col0 + wc * 64;
#pragma unroll
  for (int n = 0; n < 4; ++n) {
    const int col = colw + n * 16 + (lane & 15);
#pragma unroll
    for (int m = 0; m < 4; ++m) {
      const int rb = roww + m * 16 + ((lane >> 4) << 2);
#pragma unroll
      for (int r = 0; r < 4; ++r) {
        const size_t idx = (size_t)(rb + r) * NN + col;
        const int mk = nbr[idx];            // issue load before exp/store
        const float e = __expf(acc[m][n][r]);
        E[idx] = __float2bfloat16(e);
        rsum[m][r] += (mk != 0) ? e : 0.0f;
      }
    }
  }
  // reduce across the 16 col-lanes, then one atomic per row
#pragma unroll
  for (int m = 0; m < 4; ++m)
#pragma unroll
    for (int r = 0; r < 4; ++r) {
      float v = rsum[m][r];
      v += __shfl_xor(v, 1);
      v += __shfl_xor(v, 2);
      v += __shfl_xor(v, 4);
      v += __shfl_xor(v, 8);
      if ((lane & 15) == 0)
        atomicAdd(&summed[roww + m * 16 + ((lane >> 4) << 2) + r], v);
    }
}

// ---------------------------------------------------------------------------
__global__ void inv_kernel(const float* __restrict__ summed, float* __restrict__ inv) {
  const int j = blockIdx.x * 256 + threadIdx.x;
  inv[j] = 1.0f / summed[j];
}

// ---------------------------------------------------------------------------
// pass2: out[i,j] = float(E[i,j]) * inv[j] — pure streaming, 8 elems/thread.
// ---------------------------------------------------------------------------
__global__ __launch_bounds__(256)
void pass2_kernel(const unsigned short* __restrict__ E,
                  const float* __restrict__ inv,
                  float* __restrict__ out) {
  const size_t base = ((size_t)blockIdx.x * 256 + threadIdx.x) * 8;
  const int col = (int)(base & (NN - 1));          // 8 never crosses a row
  const u16x8 e = *(const u16x8*)(E + base);
  const f32x4 i0 = *(const f32x4*)(inv + col);
  const f32x4 i1 = *(const f32x4*)(inv + col + 4);
  f32x4 o0, o1;
#pragma unroll
  for (int j = 0; j < 4; ++j)
    o0[j] = __uint_as_float((unsigned)e[j] << 16) * i0[j];
#pragma unroll
  for (int j = 0; j < 4; ++j)
    o1[j] = __uint_as_float((unsigned)e[4 + j] << 16) * i1[j];
  *(f32x4*)(out + base)     = o0;
  *(f32x4*)(out + base + 4) = o1;
}

// ---------------------------------------------------------------------------
extern "C" void kernel_launch(void* const* d_in, const int* in_sizes, int n_in,
                              void* d_out, int out_size, void* d_ws, size_t ws_size,
                              hipStream_t stream) {
  const float* f  = (const float*)d_in[0];
  const float* wq = (const float*)d_in[1];
  const float* wk = (const float*)d_in[2];
  const int*   nbr = (const int*)d_in[3];
  float* out = (float*)d_out;

  char* ws = (char*)d_ws;
  __hip_bfloat16* G = (__hip_bfloat16*)(ws + G_OFF);
  float* summed     = (float*)(ws + SUM_OFF);
  float* inv        = (float*)(ws + INV_OFF);
  unsigned* smask   = (unsigned*)(ws + SMASK_OFF);
  __hip_bfloat16* E = (__hip_bfloat16*)(ws + E_OFF);

  prep_kernel<<<dim3(NN / 32, KD / 32), dim3(32, 8), 0, stream>>>(f, wq, wk, G);
  init_kernel<<<NN / 256, 256, 0, stream>>>(wq, wk, summed, smask);
  pass1_kernel<<<4096, 256, 0, stream>>>(G, smask, nbr, E, summed);
  inv_kernel<<<NN / 256, 256, 0, stream>>>(summed, inv);
  pass2_kernel<<<(NN * NN) / (256 * 8), 256, 0, stream>>>((const unsigned short*)E, inv, out);
}

// Round 5
// 521.267 us; speedup vs baseline: 1.0461x; 1.0461x over previous
//
#include <hip/hip_runtime.h>
#include <hip/hip_bf16.h>

// Problem constants
#define NN 8192   // nodes
#define KD 256    // feature size (GEMM K)

typedef __bf16 bf16x8 __attribute__((ext_vector_type(8)));
typedef float  f32x4  __attribute__((ext_vector_type(4)));
typedef int    i32x4  __attribute__((ext_vector_type(4)));
typedef unsigned short u16x8 __attribute__((ext_vector_type(8)));
typedef unsigned short u16x4 __attribute__((ext_vector_type(4)));

union frag_u { i32x4 i; bf16x8 b; };

// ---------------------------------------------------------------------------
// Workspace layout (ws_size >= 1 GiB confirmed by round-3/4 profiles)
//   G      bf16[NN][KD]  at 0      (4 MB)    G[i][s] = sqrt(|wq_s wk_s|) f_si
//   summed f32[NN]       at 4MB    (32 KB)
//   inv    f32[NN]       at 4MB+32K(32 KB)
//   smask  u32[KD/2]     at 4MB+64K(512 B)   bf16-pair sign masks of w_s
//   E      bf16[NN][NN]  at 8MB    (128 MB)  E[i][j] = exp(C[i][j])
// ---------------------------------------------------------------------------
#define G_OFF      0
#define SUM_OFF    (4u * 1024 * 1024)
#define INV_OFF    (SUM_OFF + 32u * 1024)
#define SMASK_OFF  (INV_OFF + 32u * 1024)
#define E_OFF      (8u * 1024 * 1024)

// RNE f32->bf16 (positive normals only here; matches pass2's <<16 decode)
__device__ __forceinline__ unsigned short f2bf(float x) {
  unsigned u = __float_as_uint(x);
  return (unsigned short)((u + 0x7fffu + ((u >> 16) & 1u)) >> 16);
}

// ---------------------------------------------------------------------------
// Stage a 128-row x 64-col bf16 tile (16 KB) into LDS via global_load_lds
// width=16, T2 XOR swizzle pre-applied on the global source (verified r3).
// ---------------------------------------------------------------------------
__device__ __forceinline__ void stage_tile(const char* src00, char* lds,
                                           int wave, int lane) {
#pragma unroll
  for (int c = 0; c < 4; ++c) {
    const int chunk = ((wave << 2) + c) << 10;       // 1 KB per wave-call
    const int o     = chunk + (lane << 4);
    const int row   = o >> 7;
    const int swb   = o & 127;
    const int colb  = swb ^ ((row & 7) << 4);        // inverse swizzle on source
    __builtin_amdgcn_global_load_lds(
        (const __attribute__((address_space(1))) void*)(src00 + (size_t)row * (KD * 2) + colb),
        (__attribute__((address_space(3))) void*)(lds + chunk),  // wave-uniform base
        16, 0, 0);
  }
}

__device__ __forceinline__ bf16x8 read_frag(const char* lds, int row, int colb) {
  const int addr = (row << 7) + (colb ^ ((row & 7) << 4));
  return *(const bf16x8*)(lds + addr);   // ds_read_b128
}

// B-side fragment with sign(w_s) applied via bf16 sign-bit XOR.
__device__ __forceinline__ bf16x8 read_frag_sgn(const char* lds, int row, int colb,
                                                i32x4 msk) {
  const int addr = (row << 7) + (colb ^ ((row & 7) << 4));
  frag_u u;
  u.i = *(const i32x4*)(lds + addr) ^ msk;
  return u.b;
}

// ---------------------------------------------------------------------------
// prep: G[i][s] = bf16( sqrt(|wq_s*wk_s|) * f[s][i] )   (transposed)
// ---------------------------------------------------------------------------
__global__ void prep_kernel(const float* __restrict__ f,
                            const float* __restrict__ wq,
                            const float* __restrict__ wk,
                            __hip_bfloat16* __restrict__ G) {
  __shared__ float tile[32][33];
  const int i0 = blockIdx.x * 32;
  const int s0 = blockIdx.y * 32;
  const int tx = threadIdx.x, ty = threadIdx.y;   // block (32, 8)
#pragma unroll
  for (int k = 0; k < 4; ++k) {
    const int s = s0 + ty + k * 8;
    tile[ty + k * 8][tx] = f[(size_t)s * NN + i0 + tx];
  }
  __syncthreads();
  const float w  = wq[s0 + tx] * wk[s0 + tx];
  const float sq = sqrtf(fabsf(w));
#pragma unroll
  for (int k = 0; k < 4; ++k) {
    const int ii = ty + k * 8;
    G[(size_t)(i0 + ii) * KD + s0 + tx] = __float2bfloat16(sq * tile[tx][ii]);
  }
}

// ---------------------------------------------------------------------------
// init: zero summed; block 0 also builds the bf16-pair sign masks of w.
// ---------------------------------------------------------------------------
__global__ void init_kernel(const float* __restrict__ wq,
                            const float* __restrict__ wk,
                            float* __restrict__ summed,
                            unsigned* __restrict__ smask) {
  const int j = blockIdx.x * 256 + threadIdx.x;
  summed[j] = 0.0f;
  if (blockIdx.x == 0 && threadIdx.x < KD / 2) {
    const int t = threadIdx.x;
    const float w0 = wq[2 * t] * wk[2 * t];
    const float w1 = wq[2 * t + 1] * wk[2 * t + 1];
    unsigned m = 0;
    if (w0 < 0.0f) m |= 0x00008000u;
    if (w1 < 0.0f) m |= 0x80000000u;
    smask[t] = m;
  }
}

// ---------------------------------------------------------------------------
// pass1: one 128x128 tile per block. GEMM (operand-SWAPPED mfma so the C/D
// layout is row-contiguous per thread) -> e=exp(C) -> E store (8B packed)
// -> masked row-sum via vectorized nbr reads -> 2 shuffles + atomics.
// Swapped layout: acc[m][n][r] sits at row = row0+wr*64+m*16+(lane&15),
//                                   col = col0+wc*64+n*16+(lane>>4)*4+r.
// ---------------------------------------------------------------------------
__global__ __launch_bounds__(256, 2)
void pass1_kernel(const __hip_bfloat16* __restrict__ G,
                  const unsigned* __restrict__ smask,
                  const int* __restrict__ nbr,
                  unsigned short* __restrict__ E,
                  float* __restrict__ summed) {
  __shared__ __attribute__((aligned(128))) char lA[16384];
  __shared__ __attribute__((aligned(128))) char lB[16384];
  __shared__ __attribute__((aligned(16))) unsigned smem_mask[KD / 2];
  const int lane = threadIdx.x & 63;
  const int wave = threadIdx.x >> 6;
  const int wr = wave >> 1, wc = wave & 1;
  const int bm = blockIdx.x >> 6;
  const int bn = blockIdx.x & 63;
  const int row0 = bm * 128;
  const int col0 = bn * 128;

  if (threadIdx.x < KD / 2) smem_mask[threadIdx.x] = smask[threadIdx.x];

  f32x4 acc[4][4] = {{}};
#pragma unroll
  for (int kk = 0; kk < KD; kk += 64) {
    stage_tile((const char*)G + (size_t)row0 * (KD * 2) + kk * 2, lA, wave, lane);
    stage_tile((const char*)G + (size_t)col0 * (KD * 2) + kk * 2, lB, wave, lane);
    asm volatile("s_waitcnt vmcnt(0)" ::: "memory");
    __syncthreads();
#pragma unroll
    for (int kh = 0; kh < 2; ++kh) {
      const int colb = kh * 64 + ((lane >> 4) << 4);
      const i32x4 msk = *(const i32x4*)&smem_mask[(kk >> 1) + kh * 16 + ((lane >> 4) << 2)];
      bf16x8 a[4], b[4];
#pragma unroll
      for (int m = 0; m < 4; ++m) a[m] = read_frag(lA, wr * 64 + m * 16 + (lane & 15), colb);
#pragma unroll
      for (int n = 0; n < 4; ++n) b[n] = read_frag_sgn(lB, wc * 64 + n * 16 + (lane & 15), colb, msk);
      // SWAPPED operands: acc holds the transposed sub-tile (row-contiguous
      // per-thread epilogue). Sign-mask on b is position-independent.
#pragma unroll
      for (int m = 0; m < 4; ++m)
#pragma unroll
        for (int n = 0; n < 4; ++n)
          acc[m][n] = __builtin_amdgcn_mfma_f32_16x16x32_bf16(b[n], a[m], acc[m][n], 0, 0, 0);
    }
    __syncthreads();
  }

  // ---- epilogue (coalesced, batched) ----
  const int lo = lane & 15, hi = lane >> 4;
  const int roww = row0 + wr * 64;
  const int colw = col0 + wc * 64;

  // batch all 16 nbr vector loads first (deep MLP)
  i32x4 nb[4][4];
#pragma unroll
  for (int m = 0; m < 4; ++m) {
    const size_t rowb = (size_t)(roww + m * 16 + lo) * NN;
#pragma unroll
    for (int n = 0; n < 4; ++n)
      nb[m][n] = *(const i32x4*)(nbr + rowb + colw + n * 16 + hi * 4);
  }

  float rsum[4];
#pragma unroll
  for (int m = 0; m < 4; ++m) {
    rsum[m] = 0.0f;
    const size_t rowb = (size_t)(roww + m * 16 + lo) * NN;
#pragma unroll
    for (int n = 0; n < 4; ++n) {
      u16x4 pk;
#pragma unroll
      for (int r = 0; r < 4; ++r) {
        const float e = __expf(acc[m][n][r]);
        pk[r] = f2bf(e);
        rsum[m] += (nb[m][n][r] != 0) ? e : 0.0f;
      }
      *(u16x4*)(E + rowb + colw + n * 16 + hi * 4) = pk;   // 8B store
    }
  }

  // reduce across the 4 hi-groups; one atomic per row from lanes 0..15
#pragma unroll
  for (int m = 0; m < 4; ++m) {
    float v = rsum[m];
    v += __shfl_xor(v, 16);
    v += __shfl_xor(v, 32);
    if (lane < 16) atomicAdd(&summed[roww + m * 16 + lo], v);
  }
}

// ---------------------------------------------------------------------------
__global__ void inv_kernel(const float* __restrict__ summed, float* __restrict__ inv) {
  const int j = blockIdx.x * 256 + threadIdx.x;
  inv[j] = 1.0f / summed[j];
}

// ---------------------------------------------------------------------------
// pass2: out[i,j] = float(E[i,j]) * inv[j] — pure streaming, 8 elems/thread.
// ---------------------------------------------------------------------------
__global__ __launch_bounds__(256)
void pass2_kernel(const unsigned short* __restrict__ E,
                  const float* __restrict__ inv,
                  float* __restrict__ out) {
  const size_t base = ((size_t)blockIdx.x * 256 + threadIdx.x) * 8;
  const int col = (int)(base & (NN - 1));          // 8 never crosses a row
  const u16x8 e = *(const u16x8*)(E + base);
  const f32x4 i0 = *(const f32x4*)(inv + col);
  const f32x4 i1 = *(const f32x4*)(inv + col + 4);
  f32x4 o0, o1;
#pragma unroll
  for (int j = 0; j < 4; ++j)
    o0[j] = __uint_as_float((unsigned)e[j] << 16) * i0[j];
#pragma unroll
  for (int j = 0; j < 4; ++j)
    o1[j] = __uint_as_float((unsigned)e[4 + j] << 16) * i1[j];
  *(f32x4*)(out + base)     = o0;
  *(f32x4*)(out + base + 4) = o1;
}

// ---------------------------------------------------------------------------
extern "C" void kernel_launch(void* const* d_in, const int* in_sizes, int n_in,
                              void* d_out, int out_size, void* d_ws, size_t ws_size,
                              hipStream_t stream) {
  const float* f  = (const float*)d_in[0];
  const float* wq = (const float*)d_in[1];
  const float* wk = (const float*)d_in[2];
  const int*   nbr = (const int*)d_in[3];
  float* out = (float*)d_out;

  char* ws = (char*)d_ws;
  __hip_bfloat16* G = (__hip_bfloat16*)(ws + G_OFF);
  float* summed     = (float*)(ws + SUM_OFF);
  float* inv        = (float*)(ws + INV_OFF);
  unsigned* smask   = (unsigned*)(ws + SMASK_OFF);
  unsigned short* E = (unsigned short*)(ws + E_OFF);

  prep_kernel<<<dim3(NN / 32, KD / 32), dim3(32, 8), 0, stream>>>(f, wq, wk, G);
  init_kernel<<<NN / 256, 256, 0, stream>>>(wq, wk, summed, smask);
  pass1_kernel<<<4096, 256, 0, stream>>>(G, smask, nbr, E, summed);
  inv_kernel<<<NN / 256, 256, 0, stream>>>(summed, inv);
  pass2_kernel<<<(NN * NN) / (256 * 8), 256, 0, stream>>>(E, inv, out);
}